// Round 1
// baseline (1010.541 us; speedup 1.0000x reference)
//
#include <hip/hip_runtime.h>

#define N_NODES 50000
#define N_EDGES 600000
#define N_GRAPHS 500
#define IN_F 92
#define HID 64
#define EDGE_F 41
#define ZDIM 169
#define PRED 128
#define BN_EPS 1e-5f

// ---------------- embed: h = x @ W_embed + b_embed ----------------
__global__ __launch_bounds__(256) void k_embed(const float* __restrict__ x,
                                               const float* __restrict__ W,
                                               const float* __restrict__ b,
                                               float* __restrict__ h) {
    __shared__ float Wl[IN_F * HID];  // 23.5 KB
    for (int idx = threadIdx.x; idx < IN_F * HID; idx += 256) Wl[idx] = W[idx];
    __syncthreads();
    const int lane = threadIdx.x & 63;
    const int wid = blockIdx.x * 4 + (threadIdx.x >> 6);
    const int nwaves = gridDim.x * 4;
    const float bj = b[lane];
    for (int r0 = wid * 4; r0 < N_NODES; r0 += nwaves * 4) {
        const float* x0 = x + (size_t)r0 * IN_F;
        float a0 = bj, a1 = bj, a2 = bj, a3 = bj;
        #pragma unroll 4
        for (int k = 0; k < IN_F; ++k) {
            float w = Wl[k * HID + lane];
            a0 += x0[k] * w;
            a1 += x0[IN_F + k] * w;
            a2 += x0[2 * IN_F + k] * w;
            a3 += x0[3 * IN_F + k] * w;
        }
        h[(size_t)(r0 + 0) * HID + lane] = a0;
        h[(size_t)(r0 + 1) * HID + lane] = a1;
        h[(size_t)(r0 + 2) * HID + lane] = a2;
        h[(size_t)(r0 + 3) * HID + lane] = a3;
    }
}

// ---------------- proj: node-side projections, residual copy, stats zero ---
// pA[n][j] = {b_sig[j] + sum_k h[n][k]*Wsig[k][j],  b_sp[j] + sum_k h[n][k]*Wsp[k][j]}
// pB[n][j] = {sum_k h[n][k]*Wsig[64+k][j],          sum_k h[n][k]*Wsp[64+k][j]}
// agg[n][j] = h[n][j]
__global__ __launch_bounds__(256) void k_proj(const float* __restrict__ h,
                                              const float* __restrict__ Wsig,
                                              const float* __restrict__ bsig,
                                              const float* __restrict__ Wsp,
                                              const float* __restrict__ bsp,
                                              float2* __restrict__ pA,
                                              float2* __restrict__ pB,
                                              float* __restrict__ agg,
                                              float* __restrict__ stats) {
    __shared__ float4 Wl[HID * HID];  // 64 KB: {sigA, spA, sigB, spB} per (k,j)
    for (int idx = threadIdx.x; idx < HID * HID; idx += 256) {
        int k = idx >> 6, j = idx & 63;
        Wl[idx] = make_float4(Wsig[k * HID + j], Wsp[k * HID + j],
                              Wsig[(HID + k) * HID + j], Wsp[(HID + k) * HID + j]);
    }
    if (blockIdx.x == 0 && threadIdx.x < 128) stats[threadIdx.x] = 0.f;
    __syncthreads();
    const int lane = threadIdx.x & 63;
    const int wid = blockIdx.x * 4 + (threadIdx.x >> 6);
    const int nwaves = gridDim.x * 4;
    const float bs = bsig[lane], bp = bsp[lane];
    for (int r0 = wid * 4; r0 < N_NODES; r0 += nwaves * 4) {
        const float* h0 = h + (size_t)r0 * HID;
        float4 a0 = make_float4(bs, bp, 0.f, 0.f);
        float4 a1 = a0, a2 = a0, a3 = a0;
        #pragma unroll 4
        for (int k = 0; k < HID; ++k) {
            float4 w = Wl[k * HID + lane];
            float h0k = h0[k], h1k = h0[HID + k], h2k = h0[2 * HID + k], h3k = h0[3 * HID + k];
            a0.x += h0k * w.x; a0.y += h0k * w.y; a0.z += h0k * w.z; a0.w += h0k * w.w;
            a1.x += h1k * w.x; a1.y += h1k * w.y; a1.z += h1k * w.z; a1.w += h1k * w.w;
            a2.x += h2k * w.x; a2.y += h2k * w.y; a2.z += h2k * w.z; a2.w += h2k * w.w;
            a3.x += h3k * w.x; a3.y += h3k * w.y; a3.z += h3k * w.z; a3.w += h3k * w.w;
        }
        size_t base = (size_t)r0 * HID + lane;
        pA[base + 0 * HID] = make_float2(a0.x, a0.y);
        pA[base + 1 * HID] = make_float2(a1.x, a1.y);
        pA[base + 2 * HID] = make_float2(a2.x, a2.y);
        pA[base + 3 * HID] = make_float2(a3.x, a3.y);
        pB[base + 0 * HID] = make_float2(a0.z, a0.w);
        pB[base + 1 * HID] = make_float2(a1.z, a1.w);
        pB[base + 2 * HID] = make_float2(a2.z, a2.w);
        pB[base + 3 * HID] = make_float2(a3.z, a3.w);
        agg[base + 0 * HID] = h0[lane];
        agg[base + 1 * HID] = h0[HID + lane];
        agg[base + 2 * HID] = h0[2 * HID + lane];
        agg[base + 3 * HID] = h0[3 * HID + lane];
    }
}

// ---------------- edge: gated messages + scatter-add ----------------
__global__ __launch_bounds__(256) void k_edge(const float2* __restrict__ pA,
                                              const float2* __restrict__ pB,
                                              const float* __restrict__ ea,
                                              const int* __restrict__ src,
                                              const int* __restrict__ dst,
                                              const float* __restrict__ Wc_sig,
                                              const float* __restrict__ Wc_sp,
                                              float* __restrict__ agg) {
    __shared__ float2 Wl[EDGE_F * HID];  // 21 KB: {sig, sp} per (k,j)
    for (int idx = threadIdx.x; idx < EDGE_F * HID; idx += 256) {
        int k = idx >> 6, j = idx & 63;
        Wl[idx] = make_float2(Wc_sig[k * HID + j], Wc_sp[k * HID + j]);
    }
    __syncthreads();
    const int lane = threadIdx.x & 63;
    const int wid = blockIdx.x * 4 + (threadIdx.x >> 6);
    const int nwaves = gridDim.x * 4;
    for (int e = wid; e < N_EDGES; e += nwaves) {
        int s = src[e], d = dst[e];
        // issue gathers early; dot-loop hides their latency
        float2 a = pA[(size_t)s * HID + lane];
        float2 b = pB[(size_t)d * HID + lane];
        const float* er = ea + (size_t)e * EDGE_F;
        float ps = 0.f, pp = 0.f;
        #pragma unroll
        for (int k = 0; k < EDGE_F; ++k) {
            float v = er[k];
            float2 w = Wl[k * HID + lane];
            ps += v * w.x;
            pp += v * w.y;
        }
        ps += a.x + b.x;
        pp += a.y + b.y;
        float g = 1.f / (1.f + __expf(-ps));
        float m = fmaxf(pp, 0.f) + __logf(1.f + __expf(-fabsf(pp)));
        unsafeAtomicAdd(&agg[(size_t)d * HID + lane], g * m);
    }
}

// ---------------- BN stats: per-feature sum / sumsq over nodes ----------------
__global__ __launch_bounds__(256) void k_stats(const float* __restrict__ agg,
                                               float* __restrict__ stats) {
    const int lane = threadIdx.x & 63;
    float s = 0.f, s2 = 0.f;
    const int stride = gridDim.x * 4;
    for (int r = blockIdx.x * 4 + (threadIdx.x >> 6); r < N_NODES; r += stride) {
        float v = agg[(size_t)r * HID + lane];
        s += v;
        s2 += v * v;
    }
    __shared__ float red[256];
    red[threadIdx.x] = s;
    __syncthreads();
    if (threadIdx.x < 64) {
        float t = red[threadIdx.x] + red[threadIdx.x + 64] + red[threadIdx.x + 128] + red[threadIdx.x + 192];
        unsafeAtomicAdd(&stats[lane], t);
    }
    __syncthreads();
    red[threadIdx.x] = s2;
    __syncthreads();
    if (threadIdx.x < 64) {
        float t = red[threadIdx.x] + red[threadIdx.x + 64] + red[threadIdx.x + 128] + red[threadIdx.x + 192];
        unsafeAtomicAdd(&stats[64 + lane], t);
    }
}

// ---------------- BN apply: h = (agg - mean) * rsqrt(var+eps) * gamma + beta --
__global__ __launch_bounds__(256) void k_bnapply(const float* __restrict__ agg,
                                                 const float* __restrict__ stats,
                                                 const float* __restrict__ gamma,
                                                 const float* __restrict__ beta,
                                                 float* __restrict__ h) {
    const int lane = threadIdx.x & 63;
    const float inv_n = 1.f / (float)N_NODES;
    float mean = stats[lane] * inv_n;
    float var = stats[64 + lane] * inv_n - mean * mean;
    float scale = rsqrtf(var + BN_EPS) * gamma[lane];
    float shift = beta[lane] - mean * scale;
    const int stride = gridDim.x * 4;
    for (int r = blockIdx.x * 4 + (threadIdx.x >> 6); r < N_NODES; r += stride) {
        size_t i = (size_t)r * HID + lane;
        h[i] = agg[i] * scale + shift;
    }
}

__global__ void k_zero(float* __restrict__ p, int n) {
    int i = blockIdx.x * blockDim.x + threadIdx.x;
    if (i < n) p[i] = 0.f;
}

// ---------------- pool: segment-sum over sorted graph_idx ----------------
__global__ __launch_bounds__(256) void k_pool(const float* __restrict__ h,
                                              const int* __restrict__ gidx,
                                              float* __restrict__ gf) {
    const int lane = threadIdx.x & 63;
    const int wid = blockIdx.x * 4 + (threadIdx.x >> 6);
    const int nwaves = gridDim.x * 4;
    const int chunk = (N_NODES + nwaves - 1) / nwaves;
    int r0 = wid * chunk;
    if (r0 >= N_NODES) return;
    int r1 = min(r0 + chunk, N_NODES);
    int gcur = gidx[r0];
    float acc = 0.f;
    for (int r = r0; r < r1; ++r) {
        int g = gidx[r];
        if (g != gcur) {
            unsafeAtomicAdd(&gf[(size_t)gcur * HID + lane], acc);
            acc = 0.f;
            gcur = g;
        }
        acc += h[(size_t)r * HID + lane];
    }
    unsafeAtomicAdd(&gf[(size_t)gcur * HID + lane], acc);
}

// ---------------- readout: gf @ W_fc + b_fc -> @ W_out + b_out ----------------
__global__ __launch_bounds__(256) void k_readout(const float* __restrict__ gf,
                                                 const float* __restrict__ Wfc,
                                                 const float* __restrict__ bfc,
                                                 const float* __restrict__ Wout,
                                                 const float* __restrict__ bout,
                                                 float* __restrict__ out) {
    const int lane = threadIdx.x & 63;
    const int g = blockIdx.x * 4 + (threadIdx.x >> 6);
    if (g >= N_GRAPHS) return;
    const float* row = gf + (size_t)g * HID;
    float p0 = bfc[lane], p1 = bfc[64 + lane];
    #pragma unroll 4
    for (int k = 0; k < HID; ++k) {
        float v = row[k];
        p0 += v * Wfc[k * PRED + lane];
        p1 += v * Wfc[k * PRED + 64 + lane];
    }
    float part = p0 * Wout[lane] + p1 * Wout[64 + lane];
    #pragma unroll
    for (int off = 32; off > 0; off >>= 1) part += __shfl_xor(part, off);
    if (lane == 0) out[g] = part + bout[0];
}

extern "C" void kernel_launch(void* const* d_in, const int* in_sizes, int n_in,
                              void* d_out, int out_size, void* d_ws, size_t ws_size,
                              hipStream_t stream) {
    const float* x         = (const float*)d_in[0];
    const float* edge_attr = (const float*)d_in[1];
    const int*   src       = (const int*)d_in[2];
    const int*   dst       = (const int*)d_in[3];
    const int*   gidx      = (const int*)d_in[4];
    // d_in[5] = n_graphs scalar (500), hardcoded
    const float* W_embed   = (const float*)d_in[6];
    const float* b_embed   = (const float*)d_in[7];
    const float* W_sig     = (const float*)d_in[8];
    const float* b_sig     = (const float*)d_in[9];
    const float* W_sp      = (const float*)d_in[10];
    const float* b_sp      = (const float*)d_in[11];
    const float* bn_gamma  = (const float*)d_in[12];
    const float* bn_beta   = (const float*)d_in[13];
    const float* W_fc      = (const float*)d_in[14];
    const float* b_fc      = (const float*)d_in[15];
    const float* W_out     = (const float*)d_in[16];
    const float* b_out     = (const float*)d_in[17];
    float* out = (float*)d_out;

    const size_t NH = (size_t)N_NODES * HID;
    float*  ws    = (float*)d_ws;
    float*  h     = ws;
    float*  agg   = h + NH;
    float2* pA    = (float2*)(agg + NH);
    float2* pB    = pA + NH;
    float*  stats = (float*)(pB + NH);
    float*  gf    = stats + 128;

    k_embed<<<512, 256, 0, stream>>>(x, W_embed, b_embed, h);

    for (int i = 0; i < 3; ++i) {
        const float* Wsig_i = W_sig + (size_t)i * ZDIM * HID;
        const float* Wsp_i  = W_sp + (size_t)i * ZDIM * HID;
        k_proj<<<512, 256, 0, stream>>>(h, Wsig_i, b_sig + i * HID, Wsp_i, b_sp + i * HID,
                                        pA, pB, agg, stats);
        k_edge<<<2048, 256, 0, stream>>>(pA, pB, edge_attr, src, dst,
                                         Wsig_i + 2 * HID * HID, Wsp_i + 2 * HID * HID, agg);
        k_stats<<<256, 256, 0, stream>>>(agg, stats);
        k_bnapply<<<512, 256, 0, stream>>>(agg, stats, bn_gamma + i * HID, bn_beta + i * HID, h);
    }

    k_zero<<<(N_GRAPHS * HID + 255) / 256, 256, 0, stream>>>(gf, N_GRAPHS * HID);
    k_pool<<<256, 256, 0, stream>>>(h, gidx, gf);
    k_readout<<<(N_GRAPHS + 3) / 4, 256, 0, stream>>>(gf, W_fc, b_fc, W_out, b_out, out);
}

// Round 2
// 954.990 us; speedup vs baseline: 1.0582x; 1.0582x over previous
//
#include <hip/hip_runtime.h>

#define N_NODES 50000
#define N_EDGES 600000
#define N_GRAPHS 500
#define IN_F 92
#define HID 64
#define EDGE_F 41
#define EA_PAD 44              // padded edge-feature width (16B-aligned rows, 11 float4)
#define ZDIM 169
#define PRED 128
#define BN_EPS 1e-5f

typedef unsigned int u32;
typedef float f32x2 __attribute__((ext_vector_type(2)));
typedef float f32x4 __attribute__((ext_vector_type(4)));

// packed f32 FMA: acc.{x,y} += a.{x,y} * b.{x,y}  (V_PK_FMA_F32, gfx90a+)
__device__ __forceinline__ void pkfma(f32x2& acc, f32x2 a, f32x2 b) {
    asm("v_pk_fma_f32 %0, %1, %2, %0" : "+v"(acc) : "v"(a), "v"(b));
}

// f32 -> bf16 round-to-nearest-even (inputs finite)
__device__ __forceinline__ u32 f2bf(float f) {
    u32 u = __float_as_uint(f);
    return (u + 0x7fffu + ((u >> 16) & 1u)) >> 16;
}

// ---------------- embed: h = x @ W_embed + b_embed ----------------
__global__ __launch_bounds__(256) void k_embed(const float* __restrict__ x,
                                               const float* __restrict__ W,
                                               const float* __restrict__ b,
                                               float* __restrict__ h) {
    __shared__ float Wl[IN_F * HID];
    for (int idx = threadIdx.x; idx < IN_F * HID; idx += 256) Wl[idx] = W[idx];
    __syncthreads();
    const int lane = threadIdx.x & 63;
    const int wid = blockIdx.x * 4 + (threadIdx.x >> 6);
    const int nwaves = gridDim.x * 4;
    const float bj = b[lane];
    for (int r0 = wid * 4; r0 < N_NODES; r0 += nwaves * 4) {
        const float* x0 = x + (size_t)r0 * IN_F;
        float a0 = bj, a1 = bj, a2 = bj, a3 = bj;
        #pragma unroll 4
        for (int k = 0; k < IN_F; ++k) {
            float w = Wl[k * HID + lane];
            a0 += x0[k] * w;
            a1 += x0[IN_F + k] * w;
            a2 += x0[2 * IN_F + k] * w;
            a3 += x0[3 * IN_F + k] * w;
        }
        h[(size_t)(r0 + 0) * HID + lane] = a0;
        h[(size_t)(r0 + 1) * HID + lane] = a1;
        h[(size_t)(r0 + 2) * HID + lane] = a2;
        h[(size_t)(r0 + 3) * HID + lane] = a3;
    }
}

// ---------------- epack: edge_attr [E,41] f32 -> padded [E,44] f32 (once) ----
__global__ __launch_bounds__(256) void k_epack(const float* __restrict__ ea,
                                               float* __restrict__ eap) {
    const int stride = gridDim.x * 256;
    for (int idx = blockIdx.x * 256 + threadIdx.x; idx < N_EDGES * EA_PAD; idx += stride) {
        int e = idx / EA_PAD;            // magic-mul div
        int k = idx - e * EA_PAD;
        eap[idx] = (k < EDGE_F) ? ea[(size_t)e * EDGE_F + k] : 0.f;
    }
}

// ---------------- proj: node-side projections (bf16-packed), residual copy ---
// pA[n*64+j] = pack_bf16{ b_sig[j] + h[n]·Wsig[0:64,j],  b_sp[j] + h[n]·Wsp[0:64,j] }
// pB[n*64+j] = pack_bf16{ h[n]·Wsig[64:128,j],           h[n]·Wsp[64:128,j] }
__global__ __launch_bounds__(256) void k_proj(const float* __restrict__ h,
                                              const float* __restrict__ Wsig,
                                              const float* __restrict__ bsig,
                                              const float* __restrict__ Wsp,
                                              const float* __restrict__ bsp,
                                              u32* __restrict__ pA,
                                              u32* __restrict__ pB,
                                              float* __restrict__ agg,
                                              float* __restrict__ stats) {
    __shared__ float4 Wl[HID * HID];  // 64 KB: {sigA, spA, sigB, spB} per (k,j)
    for (int idx = threadIdx.x; idx < HID * HID; idx += 256) {
        int k = idx >> 6, j = idx & 63;
        Wl[idx] = make_float4(Wsig[k * HID + j], Wsp[k * HID + j],
                              Wsig[(HID + k) * HID + j], Wsp[(HID + k) * HID + j]);
    }
    if (blockIdx.x == 0 && threadIdx.x < 128) stats[threadIdx.x] = 0.f;
    __syncthreads();
    const int lane = threadIdx.x & 63;
    const int wid = blockIdx.x * 4 + (threadIdx.x >> 6);
    const int nwaves = gridDim.x * 4;
    const float bs = bsig[lane], bp = bsp[lane];
    for (int r0 = wid * 4; r0 < N_NODES; r0 += nwaves * 4) {
        const float* h0 = h + (size_t)r0 * HID;
        float4 a0 = make_float4(bs, bp, 0.f, 0.f);
        float4 a1 = a0, a2 = a0, a3 = a0;
        #pragma unroll 4
        for (int k = 0; k < HID; ++k) {
            float4 w = Wl[k * HID + lane];
            float h0k = h0[k], h1k = h0[HID + k], h2k = h0[2 * HID + k], h3k = h0[3 * HID + k];
            a0.x += h0k * w.x; a0.y += h0k * w.y; a0.z += h0k * w.z; a0.w += h0k * w.w;
            a1.x += h1k * w.x; a1.y += h1k * w.y; a1.z += h1k * w.z; a1.w += h1k * w.w;
            a2.x += h2k * w.x; a2.y += h2k * w.y; a2.z += h2k * w.z; a2.w += h2k * w.w;
            a3.x += h3k * w.x; a3.y += h3k * w.y; a3.z += h3k * w.z; a3.w += h3k * w.w;
        }
        size_t base = (size_t)r0 * HID + lane;
        pA[base + 0 * HID] = f2bf(a0.x) | (f2bf(a0.y) << 16);
        pA[base + 1 * HID] = f2bf(a1.x) | (f2bf(a1.y) << 16);
        pA[base + 2 * HID] = f2bf(a2.x) | (f2bf(a2.y) << 16);
        pA[base + 3 * HID] = f2bf(a3.x) | (f2bf(a3.y) << 16);
        pB[base + 0 * HID] = f2bf(a0.z) | (f2bf(a0.w) << 16);
        pB[base + 1 * HID] = f2bf(a1.z) | (f2bf(a1.w) << 16);
        pB[base + 2 * HID] = f2bf(a2.z) | (f2bf(a2.w) << 16);
        pB[base + 3 * HID] = f2bf(a3.z) | (f2bf(a3.w) << 16);
        agg[base + 0 * HID] = h0[lane];
        agg[base + 1 * HID] = h0[HID + lane];
        agg[base + 2 * HID] = h0[2 * HID + lane];
        agg[base + 3 * HID] = h0[3 * HID + lane];
    }
}

// ---------------- edge: gated messages + scatter-add (4 edges / wave-iter) ---
__global__ __launch_bounds__(256) void k_edge(const u32* __restrict__ pA,
                                              const u32* __restrict__ pB,
                                              const f32x4* __restrict__ erp,  // [E][11]
                                              const int* __restrict__ src,
                                              const int* __restrict__ dst,
                                              const float* __restrict__ Wc_sig,
                                              const float* __restrict__ Wc_sp,
                                              float* __restrict__ agg) {
    __shared__ f32x4 Ws[11 * 64];  // 11.25 KB each: w[4k4+t][lane], zero-padded k>=41
    __shared__ f32x4 Wp[11 * 64];
    for (int idx = threadIdx.x; idx < 11 * 64; idx += 256) {
        int k4 = idx >> 6, j = idx & 63;
        f32x4 s, p;
        #pragma unroll
        for (int t = 0; t < 4; ++t) {
            int k = 4 * k4 + t;
            s[t] = (k < EDGE_F) ? Wc_sig[k * HID + j] : 0.f;
            p[t] = (k < EDGE_F) ? Wc_sp[k * HID + j] : 0.f;
        }
        Ws[idx] = s;
        Wp[idx] = p;
    }
    __syncthreads();
    const int lane = threadIdx.x & 63;
    const int wid = __builtin_amdgcn_readfirstlane((blockIdx.x << 2) + (threadIdx.x >> 6));
    const int step = gridDim.x << 4;  // nwaves * 4 edges
    for (int e0 = wid << 2; e0 < N_EDGES; e0 += step) {
        const int4 s4 = *(const int4*)(src + e0);
        const int4 d4 = *(const int4*)(dst + e0);
        u32 ga0 = pA[(size_t)s4.x * HID + lane];
        u32 ga1 = pA[(size_t)s4.y * HID + lane];
        u32 ga2 = pA[(size_t)s4.z * HID + lane];
        u32 ga3 = pA[(size_t)s4.w * HID + lane];
        u32 gb0 = pB[(size_t)d4.x * HID + lane];
        u32 gb1 = pB[(size_t)d4.y * HID + lane];
        u32 gb2 = pB[(size_t)d4.z * HID + lane];
        u32 gb3 = pB[(size_t)d4.w * HID + lane];
        const f32x4* er = erp + (size_t)e0 * 11;
        f32x2 ps0 = {0.f, 0.f}, ps1 = ps0, ps2 = ps0, ps3 = ps0;
        f32x2 pp0 = ps0, pp1 = ps0, pp2 = ps0, pp3 = ps0;
        #pragma unroll
        for (int k4 = 0; k4 < 11; ++k4) {
            f32x4 ws = Ws[(k4 << 6) + lane];   // shared by all 4 edges
            f32x4 wp = Wp[(k4 << 6) + lane];
            f32x4 e0v = er[k4];
            f32x4 e1v = er[11 + k4];
            f32x4 e2v = er[22 + k4];
            f32x4 e3v = er[33 + k4];
            pkfma(ps0, e0v.lo, ws.lo); pkfma(ps0, e0v.hi, ws.hi);
            pkfma(pp0, e0v.lo, wp.lo); pkfma(pp0, e0v.hi, wp.hi);
            pkfma(ps1, e1v.lo, ws.lo); pkfma(ps1, e1v.hi, ws.hi);
            pkfma(pp1, e1v.lo, wp.lo); pkfma(pp1, e1v.hi, wp.hi);
            pkfma(ps2, e2v.lo, ws.lo); pkfma(ps2, e2v.hi, ws.hi);
            pkfma(pp2, e2v.lo, wp.lo); pkfma(pp2, e2v.hi, wp.hi);
            pkfma(ps3, e3v.lo, ws.lo); pkfma(ps3, e3v.hi, ws.hi);
            pkfma(pp3, e3v.lo, wp.lo); pkfma(pp3, e3v.hi, wp.hi);
        }
        #define EDGE_EPI(ps, pp, ga, gb, dnode)                                    \
        {                                                                          \
            float asig = __uint_as_float(ga << 16);                                \
            float asp  = __uint_as_float(ga & 0xffff0000u);                        \
            float bsig = __uint_as_float(gb << 16);                                \
            float bsp  = __uint_as_float(gb & 0xffff0000u);                        \
            float s_ = ps.x + ps.y + asig + bsig;                                  \
            float p_ = pp.x + pp.y + asp + bsp;                                    \
            float g_ = __builtin_amdgcn_rcpf(1.f + __expf(-s_));                   \
            float m_ = fmaxf(p_, 0.f) + __logf(1.f + __expf(-fabsf(p_)));          \
            unsafeAtomicAdd(&agg[(size_t)(dnode) * HID + lane], g_ * m_);          \
        }
        EDGE_EPI(ps0, pp0, ga0, gb0, d4.x)
        EDGE_EPI(ps1, pp1, ga1, gb1, d4.y)
        EDGE_EPI(ps2, pp2, ga2, gb2, d4.z)
        EDGE_EPI(ps3, pp3, ga3, gb3, d4.w)
        #undef EDGE_EPI
    }
}

// ---------------- BN stats: per-feature sum / sumsq over nodes ----------------
__global__ __launch_bounds__(256) void k_stats(const float* __restrict__ agg,
                                               float* __restrict__ stats) {
    const int lane = threadIdx.x & 63;
    float s = 0.f, s2 = 0.f;
    const int stride = gridDim.x * 4;
    for (int r = blockIdx.x * 4 + (threadIdx.x >> 6); r < N_NODES; r += stride) {
        float v = agg[(size_t)r * HID + lane];
        s += v;
        s2 += v * v;
    }
    __shared__ float red[256];
    red[threadIdx.x] = s;
    __syncthreads();
    if (threadIdx.x < 64) {
        float t = red[threadIdx.x] + red[threadIdx.x + 64] + red[threadIdx.x + 128] + red[threadIdx.x + 192];
        unsafeAtomicAdd(&stats[lane], t);
    }
    __syncthreads();
    red[threadIdx.x] = s2;
    __syncthreads();
    if (threadIdx.x < 64) {
        float t = red[threadIdx.x] + red[threadIdx.x + 64] + red[threadIdx.x + 128] + red[threadIdx.x + 192];
        unsafeAtomicAdd(&stats[64 + lane], t);
    }
}

// ---------------- BN apply ----------------
__global__ __launch_bounds__(256) void k_bnapply(const float* __restrict__ agg,
                                                 const float* __restrict__ stats,
                                                 const float* __restrict__ gamma,
                                                 const float* __restrict__ beta,
                                                 float* __restrict__ h) {
    const int lane = threadIdx.x & 63;
    const float inv_n = 1.f / (float)N_NODES;
    float mean = stats[lane] * inv_n;
    float var = stats[64 + lane] * inv_n - mean * mean;
    float scale = rsqrtf(var + BN_EPS) * gamma[lane];
    float shift = beta[lane] - mean * scale;
    const int stride = gridDim.x * 4;
    for (int r = blockIdx.x * 4 + (threadIdx.x >> 6); r < N_NODES; r += stride) {
        size_t i = (size_t)r * HID + lane;
        h[i] = agg[i] * scale + shift;
    }
}

__global__ void k_zero(float* __restrict__ p, int n) {
    int i = blockIdx.x * blockDim.x + threadIdx.x;
    if (i < n) p[i] = 0.f;
}

// ---------------- pool: segment-sum over sorted graph_idx ----------------
__global__ __launch_bounds__(256) void k_pool(const float* __restrict__ h,
                                              const int* __restrict__ gidx,
                                              float* __restrict__ gf) {
    const int lane = threadIdx.x & 63;
    const int wid = blockIdx.x * 4 + (threadIdx.x >> 6);
    const int nwaves = gridDim.x * 4;
    const int chunk = (N_NODES + nwaves - 1) / nwaves;
    int r0 = wid * chunk;
    if (r0 >= N_NODES) return;
    int r1 = min(r0 + chunk, N_NODES);
    int gcur = gidx[r0];
    float acc = 0.f;
    for (int r = r0; r < r1; ++r) {
        int g = gidx[r];
        if (g != gcur) {
            unsafeAtomicAdd(&gf[(size_t)gcur * HID + lane], acc);
            acc = 0.f;
            gcur = g;
        }
        acc += h[(size_t)r * HID + lane];
    }
    unsafeAtomicAdd(&gf[(size_t)gcur * HID + lane], acc);
}

// ---------------- readout ----------------
__global__ __launch_bounds__(256) void k_readout(const float* __restrict__ gf,
                                                 const float* __restrict__ Wfc,
                                                 const float* __restrict__ bfc,
                                                 const float* __restrict__ Wout,
                                                 const float* __restrict__ bout,
                                                 float* __restrict__ out) {
    const int lane = threadIdx.x & 63;
    const int g = blockIdx.x * 4 + (threadIdx.x >> 6);
    if (g >= N_GRAPHS) return;
    const float* row = gf + (size_t)g * HID;
    float p0 = bfc[lane], p1 = bfc[64 + lane];
    #pragma unroll 4
    for (int k = 0; k < HID; ++k) {
        float v = row[k];
        p0 += v * Wfc[k * PRED + lane];
        p1 += v * Wfc[k * PRED + 64 + lane];
    }
    float part = p0 * Wout[lane] + p1 * Wout[64 + lane];
    #pragma unroll
    for (int off = 32; off > 0; off >>= 1) part += __shfl_xor(part, off);
    if (lane == 0) out[g] = part + bout[0];
}

extern "C" void kernel_launch(void* const* d_in, const int* in_sizes, int n_in,
                              void* d_out, int out_size, void* d_ws, size_t ws_size,
                              hipStream_t stream) {
    const float* x         = (const float*)d_in[0];
    const float* edge_attr = (const float*)d_in[1];
    const int*   src       = (const int*)d_in[2];
    const int*   dst       = (const int*)d_in[3];
    const int*   gidx      = (const int*)d_in[4];
    const float* W_embed   = (const float*)d_in[6];
    const float* b_embed   = (const float*)d_in[7];
    const float* W_sig     = (const float*)d_in[8];
    const float* b_sig     = (const float*)d_in[9];
    const float* W_sp      = (const float*)d_in[10];
    const float* b_sp      = (const float*)d_in[11];
    const float* bn_gamma  = (const float*)d_in[12];
    const float* bn_beta   = (const float*)d_in[13];
    const float* W_fc      = (const float*)d_in[14];
    const float* b_fc      = (const float*)d_in[15];
    const float* W_out     = (const float*)d_in[16];
    const float* b_out     = (const float*)d_in[17];
    float* out = (float*)d_out;

    const size_t NH = (size_t)N_NODES * HID;
    float* ws    = (float*)d_ws;
    float* h     = ws;                              // NH f32
    float* agg   = h + NH;                          // NH f32
    u32*   pA    = (u32*)(agg + NH);                // NH u32 (bf16x2)
    u32*   pB    = pA + NH;                         // NH u32
    float* eap   = (float*)(pB + NH);               // E*44 f32 (16B-aligned: 4*NH*4 bytes offset)
    float* stats = eap + (size_t)N_EDGES * EA_PAD;  // 128
    float* gf    = stats + 128;                     // G*HID

    k_embed<<<512, 256, 0, stream>>>(x, W_embed, b_embed, h);
    k_epack<<<2048, 256, 0, stream>>>(edge_attr, eap);

    for (int i = 0; i < 3; ++i) {
        const float* Wsig_i = W_sig + (size_t)i * ZDIM * HID;
        const float* Wsp_i  = W_sp + (size_t)i * ZDIM * HID;
        k_proj<<<512, 256, 0, stream>>>(h, Wsig_i, b_sig + i * HID, Wsp_i, b_sp + i * HID,
                                        pA, pB, agg, stats);
        k_edge<<<2048, 256, 0, stream>>>(pA, pB, (const f32x4*)eap, src, dst,
                                         Wsig_i + 2 * HID * HID, Wsp_i + 2 * HID * HID, agg);
        k_stats<<<256, 256, 0, stream>>>(agg, stats);
        k_bnapply<<<512, 256, 0, stream>>>(agg, stats, bn_gamma + i * HID, bn_beta + i * HID, h);
    }

    k_zero<<<(N_GRAPHS * HID + 255) / 256, 256, 0, stream>>>(gf, N_GRAPHS * HID);
    k_pool<<<256, 256, 0, stream>>>(h, gidx, gf);
    k_readout<<<(N_GRAPHS + 3) / 4, 256, 0, stream>>>(gf, W_fc, b_fc, W_out, b_out, out);
}

// Round 3
// 680.382 us; speedup vs baseline: 1.4853x; 1.4036x over previous
//
#include <hip/hip_runtime.h>

#define N_NODES 50000
#define N_EDGES 600000
#define N_GRAPHS 500
#define IN_F 92
#define HID 64
#define EDGE_F 41
#define ZDIM 169
#define PRED 128
#define BN_EPS 1e-5f
#define SCAN_BLOCKS 196          // ceil(50000/256)

typedef unsigned int u32;
typedef _Float16 f16;
typedef _Float16 f16x2 __attribute__((ext_vector_type(2)));

// f32 -> bf16 round-to-nearest-even
__device__ __forceinline__ u32 f2bf(float f) {
    u32 u = __float_as_uint(f);
    return (u + 0x7fffu + ((u >> 16) & 1u)) >> 16;
}

// f16x2 dot with f32 accumulate
__device__ __forceinline__ float dot2(u32 a, f16x2 w, float acc) {
#if __has_builtin(__builtin_amdgcn_fdot2)
    return __builtin_amdgcn_fdot2(__builtin_bit_cast(f16x2, a), w, acc, false);
#else
    f16x2 av = __builtin_bit_cast(f16x2, a);
    return acc + (float)av.x * (float)w.x + (float)av.y * (float)w.y;
#endif
}

__device__ __forceinline__ float edge_msg(float s_, float p_) {
    float g_ = __builtin_amdgcn_rcpf(1.f + __expf(-s_));
    float m_ = fmaxf(p_, 0.f) + __logf(1.f + __expf(-fabsf(p_)));
    return g_ * m_;
}

// ---------------- embed: A = x @ W_embed + b_embed ----------------
__global__ __launch_bounds__(256) void k_embed(const float* __restrict__ x,
                                               const float* __restrict__ W,
                                               const float* __restrict__ b,
                                               float* __restrict__ A) {
    __shared__ float Wl[IN_F * HID];
    for (int idx = threadIdx.x; idx < IN_F * HID; idx += 256) Wl[idx] = W[idx];
    __syncthreads();
    const int lane = threadIdx.x & 63;
    const int wid = blockIdx.x * 4 + (threadIdx.x >> 6);
    const int nwaves = gridDim.x * 4;
    const float bj = b[lane];
    for (int r0 = wid * 4; r0 < N_NODES; r0 += nwaves * 4) {
        const float* x0 = x + (size_t)r0 * IN_F;
        float a0 = bj, a1 = bj, a2 = bj, a3 = bj;
        #pragma unroll 4
        for (int k = 0; k < IN_F; ++k) {
            float w = Wl[k * HID + lane];
            a0 += x0[k] * w;
            a1 += x0[IN_F + k] * w;
            a2 += x0[2 * IN_F + k] * w;
            a3 += x0[3 * IN_F + k] * w;
        }
        A[(size_t)(r0 + 0) * HID + lane] = a0;
        A[(size_t)(r0 + 1) * HID + lane] = a1;
        A[(size_t)(r0 + 2) * HID + lane] = a2;
        A[(size_t)(r0 + 3) * HID + lane] = a3;
    }
}

// ---------------- CSR build ----------------
__global__ void k_zeroi(int* __restrict__ p, int n) {
    int i = blockIdx.x * 256 + threadIdx.x;
    if (i < n) p[i] = 0;
}

__global__ void k_hist(const int* __restrict__ dst, int* __restrict__ deg) {
    int e = blockIdx.x * 256 + threadIdx.x;
    if (e < N_EDGES) atomicAdd(&deg[dst[e]], 1);
}

__global__ __launch_bounds__(256) void k_scanA(const int* __restrict__ deg,
                                               int* __restrict__ partial) {
    __shared__ int s[256];
    int i = blockIdx.x * 256 + threadIdx.x;
    s[threadIdx.x] = (i < N_NODES) ? deg[i] : 0;
    __syncthreads();
    for (int off = 128; off > 0; off >>= 1) {
        if (threadIdx.x < off) s[threadIdx.x] += s[threadIdx.x + off];
        __syncthreads();
    }
    if (threadIdx.x == 0) partial[blockIdx.x] = s[0];
}

__global__ __launch_bounds__(256) void k_scanB(const int* __restrict__ partial,
                                               int* __restrict__ partialExc,
                                               int* __restrict__ rowptr) {
    __shared__ int s[256];
    int t = threadIdx.x;
    int v = (t < SCAN_BLOCKS) ? partial[t] : 0;
    s[t] = v;
    __syncthreads();
    for (int off = 1; off < 256; off <<= 1) {
        int x = (t >= off) ? s[t - off] : 0;
        __syncthreads();
        s[t] += x;
        __syncthreads();
    }
    partialExc[t] = s[t] - v;
    if (t == 0) rowptr[N_NODES] = N_EDGES;
}

__global__ __launch_bounds__(256) void k_scanC(const int* __restrict__ deg,
                                               const int* __restrict__ partialExc,
                                               int* __restrict__ rowptr) {
    __shared__ int s[256];
    int i = blockIdx.x * 256 + threadIdx.x;
    int t = threadIdx.x;
    int v = (i < N_NODES) ? deg[i] : 0;
    s[t] = v;
    __syncthreads();
    for (int off = 1; off < 256; off <<= 1) {
        int x = (t >= off) ? s[t - off] : 0;
        __syncthreads();
        s[t] += x;
        __syncthreads();
    }
    if (i < N_NODES) rowptr[i] = s[t] - v + partialExc[blockIdx.x];
}

__global__ void k_rank(const int* __restrict__ dst, const int* __restrict__ src,
                       const int* __restrict__ rowptr, int* __restrict__ cursor,
                       int* __restrict__ iperm, int* __restrict__ srcS) {
    int e = blockIdx.x * 256 + threadIdx.x;
    if (e >= N_EDGES) return;
    int d = dst[e];
    int p = rowptr[d] + atomicAdd(&cursor[d], 1);
    iperm[p] = e;
    srcS[p] = src[e];
}

// ---------------- epackS: ea rows -> dst-sorted, f16, padded to 48 ----------
__global__ void k_epackS(const float* __restrict__ ea, const int* __restrict__ iperm,
                         u32* __restrict__ eapS) {
    int idx = blockIdx.x * 256 + threadIdx.x;
    if (idx >= N_EDGES * 24) return;
    unsigned p = (unsigned)idx / 24u;
    int q = idx - (int)p * 24;
    int e = iperm[p];
    int k0 = 2 * q, k1 = k0 + 1;
    float f0 = (k0 < EDGE_F) ? ea[(size_t)e * EDGE_F + k0] : 0.f;
    float f1 = (k1 < EDGE_F) ? ea[(size_t)e * EDGE_F + k1] : 0.f;
    f16x2 hv = {(f16)f0, (f16)f1};
    eapS[idx] = __builtin_bit_cast(u32, hv);
}

// ---------------- proj: (optional BN of A) -> pA, pB (bf16-packed); zero stats
__global__ __launch_bounds__(256) void k_proj(const float* __restrict__ A,
                                              const float* __restrict__ statsPrev,
                                              const float* __restrict__ gammaP,
                                              const float* __restrict__ betaP,
                                              int applyBN,
                                              const float* __restrict__ Wsig,
                                              const float* __restrict__ bsig,
                                              const float* __restrict__ Wsp,
                                              const float* __restrict__ bsp,
                                              u32* __restrict__ pA,
                                              u32* __restrict__ pB,
                                              float* __restrict__ statsOut) {
    __shared__ float4 Wl[HID * HID];  // {sigA, spA, sigB, spB}
    __shared__ float sc[HID], sh[HID];
    if (threadIdx.x < HID) {
        float scv = 1.f, shv = 0.f;
        if (applyBN) {
            float m = statsPrev[threadIdx.x * 32] * (1.f / N_NODES);
            float v = statsPrev[(64 + threadIdx.x) * 32] * (1.f / N_NODES) - m * m;
            scv = rsqrtf(v + BN_EPS) * gammaP[threadIdx.x];
            shv = betaP[threadIdx.x] - m * scv;
        }
        sc[threadIdx.x] = scv;
        sh[threadIdx.x] = shv;
    }
    if (blockIdx.x == 0)
        for (int i = threadIdx.x; i < 128 * 32; i += 256) statsOut[i] = 0.f;
    for (int idx = threadIdx.x; idx < HID * HID; idx += 256) {
        int k = idx >> 6, j = idx & 63;
        Wl[idx] = make_float4(Wsig[k * HID + j], Wsp[k * HID + j],
                              Wsig[(HID + k) * HID + j], Wsp[(HID + k) * HID + j]);
    }
    __syncthreads();
    const int lane = threadIdx.x & 63;
    const int wid = blockIdx.x * 4 + (threadIdx.x >> 6);
    const int nwaves = gridDim.x * 4;
    const float bs = bsig[lane], bp = bsp[lane];
    for (int r0 = wid * 4; r0 < N_NODES; r0 += nwaves * 4) {
        const float* h0 = A + (size_t)r0 * HID;
        float4 a0 = make_float4(bs, bp, 0.f, 0.f);
        float4 a1 = a0, a2 = a0, a3 = a0;
        #pragma unroll 4
        for (int k = 0; k < HID; ++k) {
            float4 w = Wl[k * HID + lane];
            float sck = sc[k], shk = sh[k];
            float h0k = h0[k] * sck + shk;
            float h1k = h0[HID + k] * sck + shk;
            float h2k = h0[2 * HID + k] * sck + shk;
            float h3k = h0[3 * HID + k] * sck + shk;
            a0.x += h0k * w.x; a0.y += h0k * w.y; a0.z += h0k * w.z; a0.w += h0k * w.w;
            a1.x += h1k * w.x; a1.y += h1k * w.y; a1.z += h1k * w.z; a1.w += h1k * w.w;
            a2.x += h2k * w.x; a2.y += h2k * w.y; a2.z += h2k * w.z; a2.w += h2k * w.w;
            a3.x += h3k * w.x; a3.y += h3k * w.y; a3.z += h3k * w.z; a3.w += h3k * w.w;
        }
        size_t base = (size_t)r0 * HID + lane;
        pA[base + 0 * HID] = f2bf(a0.x) | (f2bf(a0.y) << 16);
        pA[base + 1 * HID] = f2bf(a1.x) | (f2bf(a1.y) << 16);
        pA[base + 2 * HID] = f2bf(a2.x) | (f2bf(a2.y) << 16);
        pA[base + 3 * HID] = f2bf(a3.x) | (f2bf(a3.y) << 16);
        pB[base + 0 * HID] = f2bf(a0.z) | (f2bf(a0.w) << 16);
        pB[base + 1 * HID] = f2bf(a1.z) | (f2bf(a1.w) << 16);
        pB[base + 2 * HID] = f2bf(a2.z) | (f2bf(a2.w) << 16);
        pB[base + 3 * HID] = f2bf(a3.z) | (f2bf(a3.w) << 16);
    }
}

// ---------------- nodeagg: per-node gather-reduce, residual, BN stats --------
#define DOTQ(EV, T)                                                       \
    ds0 = dot2(EV.x, wsg[4 * T + 0], ds0);                                \
    ds1 = dot2(EV.y, wsg[4 * T + 1], ds1);                                \
    ds0 = dot2(EV.z, wsg[4 * T + 2], ds0);                                \
    ds1 = dot2(EV.w, wsg[4 * T + 3], ds1);                                \
    dp0 = dot2(EV.x, wsp[4 * T + 0], dp0);                                \
    dp1 = dot2(EV.y, wsp[4 * T + 1], dp1);                                \
    dp0 = dot2(EV.z, wsp[4 * T + 2], dp0);                                \
    dp1 = dot2(EV.w, wsp[4 * T + 3], dp1);

__global__ __launch_bounds__(256) void k_nodeagg(const float* __restrict__ A,
                                                 const float* __restrict__ statsPrev,
                                                 const float* __restrict__ gammaP,
                                                 const float* __restrict__ betaP,
                                                 int applyBN,
                                                 const u32* __restrict__ pA,
                                                 const u32* __restrict__ pB,
                                                 const u32* __restrict__ eapS,
                                                 const int* __restrict__ srcS,
                                                 const int* __restrict__ rowptr,
                                                 const float* __restrict__ We_sig,
                                                 const float* __restrict__ We_sp,
                                                 float* __restrict__ Aout,
                                                 float* __restrict__ statsOut) {
    const int lane = threadIdx.x & 63;
    f16x2 wsg[24], wsp[24];
    #pragma unroll
    for (int kp = 0; kp < 24; ++kp) {
        int k0 = 2 * kp, k1 = k0 + 1;
        float s0 = (k0 < EDGE_F) ? We_sig[k0 * HID + lane] : 0.f;
        float s1 = (k1 < EDGE_F) ? We_sig[k1 * HID + lane] : 0.f;
        float p0 = (k0 < EDGE_F) ? We_sp[k0 * HID + lane] : 0.f;
        float p1 = (k1 < EDGE_F) ? We_sp[k1 * HID + lane] : 0.f;
        wsg[kp] = {(f16)s0, (f16)s1};
        wsp[kp] = {(f16)p0, (f16)p1};
    }
    float scL = 1.f, shL = 0.f;
    if (applyBN) {
        float m = statsPrev[lane * 32] * (1.f / N_NODES);
        float v = statsPrev[(64 + lane) * 32] * (1.f / N_NODES) - m * m;
        scL = rsqrtf(v + BN_EPS) * gammaP[lane];
        shL = betaP[lane] - m * scL;
    }
    float lsum = 0.f, lsq = 0.f;
    const int wid0 = (blockIdx.x << 2) + (threadIdx.x >> 6);
    const int nw = gridDim.x << 2;
    for (int n0 = wid0; n0 < N_NODES; n0 += nw) {
        const int n = __builtin_amdgcn_readfirstlane(n0);
        const int rb = rowptr[n], re = rowptr[n + 1];
        float resid = A[(size_t)n * HID + lane];
        if (applyBN) resid = resid * scL + shL;
        u32 pb = pB[(size_t)n * HID + lane];
        const float bsig = __uint_as_float(pb << 16);
        const float bsp = __uint_as_float(pb & 0xffff0000u);
        float acc = resid;
        int e = rb;
        for (; e + 2 <= re; e += 2) {
            int s0 = srcS[e], s1 = srcS[e + 1];
            u32 ga0 = pA[(size_t)s0 * HID + lane];
            u32 ga1 = pA[(size_t)s1 * HID + lane];
            const uint4* er = (const uint4*)(eapS + (size_t)e * 24);
            uint4 e00 = er[0], e01 = er[1], e02 = er[2], e03 = er[3], e04 = er[4], e05 = er[5];
            uint4 e10 = er[6], e11 = er[7], e12 = er[8], e13 = er[9], e14 = er[10], e15 = er[11];
            {
                float ds0 = 0.f, ds1 = 0.f, dp0 = 0.f, dp1 = 0.f;
                DOTQ(e00, 0) DOTQ(e01, 1) DOTQ(e02, 2) DOTQ(e03, 3) DOTQ(e04, 4) DOTQ(e05, 5)
                float s_ = ds0 + ds1 + __uint_as_float(ga0 << 16) + bsig;
                float p_ = dp0 + dp1 + __uint_as_float(ga0 & 0xffff0000u) + bsp;
                acc += edge_msg(s_, p_);
            }
            {
                float ds0 = 0.f, ds1 = 0.f, dp0 = 0.f, dp1 = 0.f;
                DOTQ(e10, 0) DOTQ(e11, 1) DOTQ(e12, 2) DOTQ(e13, 3) DOTQ(e14, 4) DOTQ(e15, 5)
                float s_ = ds0 + ds1 + __uint_as_float(ga1 << 16) + bsig;
                float p_ = dp0 + dp1 + __uint_as_float(ga1 & 0xffff0000u) + bsp;
                acc += edge_msg(s_, p_);
            }
        }
        if (e < re) {
            int s0 = srcS[e];
            u32 ga0 = pA[(size_t)s0 * HID + lane];
            const uint4* er = (const uint4*)(eapS + (size_t)e * 24);
            uint4 e00 = er[0], e01 = er[1], e02 = er[2], e03 = er[3], e04 = er[4], e05 = er[5];
            float ds0 = 0.f, ds1 = 0.f, dp0 = 0.f, dp1 = 0.f;
            DOTQ(e00, 0) DOTQ(e01, 1) DOTQ(e02, 2) DOTQ(e03, 3) DOTQ(e04, 4) DOTQ(e05, 5)
            float s_ = ds0 + ds1 + __uint_as_float(ga0 << 16) + bsig;
            float p_ = dp0 + dp1 + __uint_as_float(ga0 & 0xffff0000u) + bsp;
            acc += edge_msg(s_, p_);
        }
        Aout[(size_t)n * HID + lane] = acc;
        lsum += acc;
        lsq += acc * acc;
    }
    __shared__ float redS[256], redQ[256];
    redS[threadIdx.x] = lsum;
    redQ[threadIdx.x] = lsq;
    __syncthreads();
    if (threadIdx.x < 64) {
        float s = redS[threadIdx.x] + redS[threadIdx.x + 64] + redS[threadIdx.x + 128] + redS[threadIdx.x + 192];
        float q = redQ[threadIdx.x] + redQ[threadIdx.x + 64] + redQ[threadIdx.x + 128] + redQ[threadIdx.x + 192];
        unsafeAtomicAdd(&statsOut[threadIdx.x * 32], s);
        unsafeAtomicAdd(&statsOut[(64 + threadIdx.x) * 32], q);
    }
}

__global__ void k_zerof(float* __restrict__ p, int n) {
    int i = blockIdx.x * blockDim.x + threadIdx.x;
    if (i < n) p[i] = 0.f;
}

// ---------------- pool (+ final BN): segment-sum over sorted graph_idx ------
__global__ __launch_bounds__(256) void k_poolbn(const float* __restrict__ A,
                                                const float* __restrict__ stats,
                                                const float* __restrict__ gamma,
                                                const float* __restrict__ beta,
                                                const int* __restrict__ gidx,
                                                float* __restrict__ gf) {
    const int lane = threadIdx.x & 63;
    float m = stats[lane * 32] * (1.f / N_NODES);
    float v = stats[(64 + lane) * 32] * (1.f / N_NODES) - m * m;
    float scv = rsqrtf(v + BN_EPS) * gamma[lane];
    float shv = beta[lane] - m * scv;
    const int wid = blockIdx.x * 4 + (threadIdx.x >> 6);
    const int nwaves = gridDim.x * 4;
    const int chunk = (N_NODES + nwaves - 1) / nwaves;
    int r0 = wid * chunk;
    if (r0 >= N_NODES) return;
    int r1 = min(r0 + chunk, N_NODES);
    int gcur = gidx[r0];
    float acc = 0.f;
    for (int r = r0; r < r1; ++r) {
        int g = gidx[r];
        if (g != gcur) {
            unsafeAtomicAdd(&gf[(size_t)gcur * HID + lane], acc);
            acc = 0.f;
            gcur = g;
        }
        acc += A[(size_t)r * HID + lane] * scv + shv;
    }
    unsafeAtomicAdd(&gf[(size_t)gcur * HID + lane], acc);
}

// ---------------- readout ----------------
__global__ __launch_bounds__(256) void k_readout(const float* __restrict__ gf,
                                                 const float* __restrict__ Wfc,
                                                 const float* __restrict__ bfc,
                                                 const float* __restrict__ Wout,
                                                 const float* __restrict__ bout,
                                                 float* __restrict__ out) {
    const int lane = threadIdx.x & 63;
    const int g = blockIdx.x * 4 + (threadIdx.x >> 6);
    if (g >= N_GRAPHS) return;
    const float* row = gf + (size_t)g * HID;
    float p0 = bfc[lane], p1 = bfc[64 + lane];
    #pragma unroll 4
    for (int k = 0; k < HID; ++k) {
        float v = row[k];
        p0 += v * Wfc[k * PRED + lane];
        p1 += v * Wfc[k * PRED + 64 + lane];
    }
    float part = p0 * Wout[lane] + p1 * Wout[64 + lane];
    #pragma unroll
    for (int off = 32; off > 0; off >>= 1) part += __shfl_xor(part, off);
    if (lane == 0) out[g] = part + bout[0];
}

extern "C" void kernel_launch(void* const* d_in, const int* in_sizes, int n_in,
                              void* d_out, int out_size, void* d_ws, size_t ws_size,
                              hipStream_t stream) {
    const float* x         = (const float*)d_in[0];
    const float* edge_attr = (const float*)d_in[1];
    const int*   src       = (const int*)d_in[2];
    const int*   dst       = (const int*)d_in[3];
    const int*   gidx      = (const int*)d_in[4];
    const float* W_embed   = (const float*)d_in[6];
    const float* b_embed   = (const float*)d_in[7];
    const float* W_sig     = (const float*)d_in[8];
    const float* b_sig     = (const float*)d_in[9];
    const float* W_sp      = (const float*)d_in[10];
    const float* b_sp      = (const float*)d_in[11];
    const float* bn_gamma  = (const float*)d_in[12];
    const float* bn_beta   = (const float*)d_in[13];
    const float* W_fc      = (const float*)d_in[14];
    const float* b_fc      = (const float*)d_in[15];
    const float* W_out     = (const float*)d_in[16];
    const float* b_out     = (const float*)d_in[17];
    float* out = (float*)d_out;

    const size_t NH = (size_t)N_NODES * HID;
    float* ws     = (float*)d_ws;
    float* A      = ws;                               // NH f32
    u32*   pA     = (u32*)(A + NH);                   // NH u32 (bf16x2)
    u32*   pB     = pA + NH;                          // NH u32
    u32*   eapS   = pB + NH;                          // E*24 u32 (f16, dst-sorted)
    int*   iperm  = (int*)(eapS + (size_t)N_EDGES * 24);  // E
    int*   srcS   = iperm + N_EDGES;                  // E
    int*   rowptr = srcS + N_EDGES;                   // N+1
    int*   deg    = rowptr + N_NODES + 1;             // N
    int*   cursor = deg + N_NODES;                    // N
    int*   partial    = cursor + N_NODES;             // 256
    int*   partialExc = partial + 256;                // 256
    float* stats  = (float*)(partialExc + 256);       // 3 * 4096 f32
    float* gf     = stats + 3 * 4096;                 // G*HID

    k_embed<<<512, 256, 0, stream>>>(x, W_embed, b_embed, A);

    // ---- CSR build (once per call) ----
    k_zeroi<<<(2 * N_NODES + 255) / 256, 256, 0, stream>>>(deg, 2 * N_NODES);  // deg+cursor
    k_hist<<<(N_EDGES + 255) / 256, 256, 0, stream>>>(dst, deg);
    k_scanA<<<SCAN_BLOCKS, 256, 0, stream>>>(deg, partial);
    k_scanB<<<1, 256, 0, stream>>>(partial, partialExc, rowptr);
    k_scanC<<<SCAN_BLOCKS, 256, 0, stream>>>(deg, partialExc, rowptr);
    k_rank<<<(N_EDGES + 255) / 256, 256, 0, stream>>>(dst, src, rowptr, cursor, iperm, srcS);
    k_epackS<<<(N_EDGES * 24 + 255) / 256, 256, 0, stream>>>(edge_attr, iperm, eapS);

    for (int i = 0; i < 3; ++i) {
        const float* Wsig_i = W_sig + (size_t)i * ZDIM * HID;
        const float* Wsp_i  = W_sp + (size_t)i * ZDIM * HID;
        const float* stPrev = stats + (size_t)(i > 0 ? i - 1 : 0) * 4096;
        const float* gP     = bn_gamma + (i > 0 ? i - 1 : 0) * HID;
        const float* bP     = bn_beta + (i > 0 ? i - 1 : 0) * HID;
        float* stOut        = stats + (size_t)i * 4096;
        int applyBN = (i > 0) ? 1 : 0;
        k_proj<<<512, 256, 0, stream>>>(A, stPrev, gP, bP, applyBN,
                                        Wsig_i, b_sig + i * HID, Wsp_i, b_sp + i * HID,
                                        pA, pB, stOut);
        k_nodeagg<<<2048, 256, 0, stream>>>(A, stPrev, gP, bP, applyBN,
                                            pA, pB, eapS, srcS, rowptr,
                                            Wsig_i + 2 * HID * HID, Wsp_i + 2 * HID * HID,
                                            A, stOut);
    }

    k_zerof<<<(N_GRAPHS * HID + 255) / 256, 256, 0, stream>>>(gf, N_GRAPHS * HID);
    k_poolbn<<<256, 256, 0, stream>>>(A, stats + 2 * 4096, bn_gamma + 2 * HID,
                                      bn_beta + 2 * HID, gidx, gf);
    k_readout<<<(N_GRAPHS + 3) / 4, 256, 0, stream>>>(gf, W_fc, b_fc, W_out, b_out, out);
}

// Round 4
// 600.551 us; speedup vs baseline: 1.6827x; 1.1329x over previous
//
#include <hip/hip_runtime.h>

#define N_NODES 50000
#define N_EDGES 600000
#define N_GRAPHS 500
#define IN_F 92
#define HID 64
#define EDGE_F 41
#define ZDIM 169
#define PRED 128
#define BN_EPS 1e-5f
#define SCAN_BLOCKS 196          // ceil(50000/256)

typedef unsigned int u32;
typedef _Float16 f16;
typedef _Float16 f16x2 __attribute__((ext_vector_type(2)));
typedef _Float16 f16x8 __attribute__((ext_vector_type(8)));
typedef float f32x4 __attribute__((ext_vector_type(4)));

// f32 -> bf16 round-to-nearest-even
__device__ __forceinline__ u32 f2bf(float f) {
    u32 u = __float_as_uint(f);
    return (u + 0x7fffu + ((u >> 16) & 1u)) >> 16;
}

__device__ __forceinline__ float edge_msg(float s_, float p_) {
    float g_ = __builtin_amdgcn_rcpf(1.f + __expf(-s_));
    float m_ = fmaxf(p_, 0.f) + __logf(1.f + __expf(-fabsf(p_)));
    return g_ * m_;
}

// ---------------- embed: A = x @ W_embed + b_embed ----------------
__global__ __launch_bounds__(256) void k_embed(const float* __restrict__ x,
                                               const float* __restrict__ W,
                                               const float* __restrict__ b,
                                               float* __restrict__ A) {
    __shared__ float Wl[IN_F * HID];
    for (int idx = threadIdx.x; idx < IN_F * HID; idx += 256) Wl[idx] = W[idx];
    __syncthreads();
    const int lane = threadIdx.x & 63;
    const int wid = blockIdx.x * 4 + (threadIdx.x >> 6);
    const int nwaves = gridDim.x * 4;
    const float bj = b[lane];
    for (int r0 = wid * 4; r0 < N_NODES; r0 += nwaves * 4) {
        const float* x0 = x + (size_t)r0 * IN_F;
        float a0 = bj, a1 = bj, a2 = bj, a3 = bj;
        #pragma unroll 4
        for (int k = 0; k < IN_F; ++k) {
            float w = Wl[k * HID + lane];
            a0 += x0[k] * w;
            a1 += x0[IN_F + k] * w;
            a2 += x0[2 * IN_F + k] * w;
            a3 += x0[3 * IN_F + k] * w;
        }
        A[(size_t)(r0 + 0) * HID + lane] = a0;
        A[(size_t)(r0 + 1) * HID + lane] = a1;
        A[(size_t)(r0 + 2) * HID + lane] = a2;
        A[(size_t)(r0 + 3) * HID + lane] = a3;
    }
}

// ---------------- CSR build ----------------
__global__ void k_zeroi(int* __restrict__ p, int n) {
    int i = blockIdx.x * 256 + threadIdx.x;
    if (i < n) p[i] = 0;
}

__global__ void k_hist(const int* __restrict__ dst, int* __restrict__ deg) {
    int e = blockIdx.x * 256 + threadIdx.x;
    if (e < N_EDGES) atomicAdd(&deg[dst[e]], 1);
}

__global__ __launch_bounds__(256) void k_scanA(const int* __restrict__ deg,
                                               int* __restrict__ partial) {
    __shared__ int s[256];
    int i = blockIdx.x * 256 + threadIdx.x;
    s[threadIdx.x] = (i < N_NODES) ? deg[i] : 0;
    __syncthreads();
    for (int off = 128; off > 0; off >>= 1) {
        if (threadIdx.x < off) s[threadIdx.x] += s[threadIdx.x + off];
        __syncthreads();
    }
    if (threadIdx.x == 0) partial[blockIdx.x] = s[0];
}

__global__ __launch_bounds__(256) void k_scanB(const int* __restrict__ partial,
                                               int* __restrict__ partialExc,
                                               int* __restrict__ rowptr) {
    __shared__ int s[256];
    int t = threadIdx.x;
    int v = (t < SCAN_BLOCKS) ? partial[t] : 0;
    s[t] = v;
    __syncthreads();
    for (int off = 1; off < 256; off <<= 1) {
        int x = (t >= off) ? s[t - off] : 0;
        __syncthreads();
        s[t] += x;
        __syncthreads();
    }
    partialExc[t] = s[t] - v;
    if (t == 0) rowptr[N_NODES] = N_EDGES;
}

__global__ __launch_bounds__(256) void k_scanC(const int* __restrict__ deg,
                                               const int* __restrict__ partialExc,
                                               int* __restrict__ rowptr) {
    __shared__ int s[256];
    int i = blockIdx.x * 256 + threadIdx.x;
    int t = threadIdx.x;
    int v = (i < N_NODES) ? deg[i] : 0;
    s[t] = v;
    __syncthreads();
    for (int off = 1; off < 256; off <<= 1) {
        int x = (t >= off) ? s[t - off] : 0;
        __syncthreads();
        s[t] += x;
        __syncthreads();
    }
    if (i < N_NODES) rowptr[i] = s[t] - v + partialExc[blockIdx.x];
}

// ---------------- rank + pack fused: place edge in CSR slot, convert row to f16
// eapS rows padded to 128 B (64 f16: feats 0..40, zeros 41..63)
__global__ void k_rank(const int* __restrict__ dst, const int* __restrict__ src,
                       const float* __restrict__ ea,
                       const int* __restrict__ rowptr, int* __restrict__ cursor,
                       int* __restrict__ srcS, u32* __restrict__ eapS) {
    int e = blockIdx.x * 256 + threadIdx.x;
    if (e >= N_EDGES) return;
    int d = dst[e];
    int p = rowptr[d] + atomicAdd(&cursor[d], 1);
    srcS[p] = src[e];
    const float* row = ea + (size_t)e * EDGE_F;
    u32 buf[32];
    #pragma unroll
    for (int q = 0; q < 32; ++q) {
        int k0 = 2 * q, k1 = k0 + 1;
        f16x2 hv = {(f16)((k0 < EDGE_F) ? row[k0] : 0.f),
                    (f16)((k1 < EDGE_F) ? row[k1] : 0.f)};
        buf[q] = __builtin_bit_cast(u32, hv);
    }
    uint4* orow = (uint4*)(eapS + (size_t)p * 32);
    #pragma unroll
    for (int q8 = 0; q8 < 8; ++q8)
        orow[q8] = make_uint4(buf[4 * q8], buf[4 * q8 + 1], buf[4 * q8 + 2], buf[4 * q8 + 3]);
}

// ---------------- wprep: edge-weight rows -> MFMA B-fragment order, f16 ------
// Wf16[L][kt][jt][lane][8 f16]; B[k][j]: k = kt*32 + (lane>>4)*8 + b (0 for k>=41),
// j = jt*16 + (lane&15); j<64 -> sig, else sp.
__global__ void k_wprep(const float* __restrict__ Wsig, const float* __restrict__ Wsp,
                        f16* __restrict__ Wf16) {
    int t = blockIdx.x * 256 + threadIdx.x;
    if (t >= 3 * 2 * 8 * 64) return;
    int lane = t & 63;
    int jt = (t >> 6) & 7;
    int kt = (t >> 9) & 1;
    int L = t >> 10;
    int j128 = jt * 16 + (lane & 15);
    const float* Wbase = (j128 < 64) ? Wsig : Wsp;
    int j = j128 & 63;
    f16x8 v;
    #pragma unroll
    for (int b = 0; b < 8; ++b) {
        int k = kt * 32 + (lane >> 4) * 8 + b;
        float f = (k < EDGE_F) ? Wbase[(size_t)L * ZDIM * HID + (128 + k) * HID + j] : 0.f;
        v[b] = (f16)f;
    }
    *(f16x8*)(Wf16 + ((size_t)((L * 2 + kt) * 8 + jt) * 64 + lane) * 8) = v;
}

// ---------------- proj: (optional BN of A) -> pA, pB (bf16-packed); zero stats
__global__ __launch_bounds__(256) void k_proj(const float* __restrict__ A,
                                              const float* __restrict__ statsPrev,
                                              const float* __restrict__ gammaP,
                                              const float* __restrict__ betaP,
                                              int applyBN,
                                              const float* __restrict__ Wsig,
                                              const float* __restrict__ bsig,
                                              const float* __restrict__ Wsp,
                                              const float* __restrict__ bsp,
                                              u32* __restrict__ pA,
                                              u32* __restrict__ pB,
                                              float* __restrict__ statsOut) {
    __shared__ float4 Wl[HID * HID];  // {sigA, spA, sigB, spB}
    __shared__ float sc[HID], sh[HID];
    if (threadIdx.x < HID) {
        float scv = 1.f, shv = 0.f;
        if (applyBN) {
            float m = statsPrev[threadIdx.x * 32] * (1.f / N_NODES);
            float v = statsPrev[(64 + threadIdx.x) * 32] * (1.f / N_NODES) - m * m;
            scv = rsqrtf(v + BN_EPS) * gammaP[threadIdx.x];
            shv = betaP[threadIdx.x] - m * scv;
        }
        sc[threadIdx.x] = scv;
        sh[threadIdx.x] = shv;
    }
    if (blockIdx.x == 0)
        for (int i = threadIdx.x; i < 128 * 32; i += 256) statsOut[i] = 0.f;
    for (int idx = threadIdx.x; idx < HID * HID; idx += 256) {
        int k = idx >> 6, j = idx & 63;
        Wl[idx] = make_float4(Wsig[k * HID + j], Wsp[k * HID + j],
                              Wsig[(HID + k) * HID + j], Wsp[(HID + k) * HID + j]);
    }
    __syncthreads();
    const int lane = threadIdx.x & 63;
    const int wid = blockIdx.x * 4 + (threadIdx.x >> 6);
    const int nwaves = gridDim.x * 4;
    const float bs = bsig[lane], bp = bsp[lane];
    for (int r0 = wid * 4; r0 < N_NODES; r0 += nwaves * 4) {
        const float* h0 = A + (size_t)r0 * HID;
        float4 a0 = make_float4(bs, bp, 0.f, 0.f);
        float4 a1 = a0, a2 = a0, a3 = a0;
        #pragma unroll 4
        for (int k = 0; k < HID; ++k) {
            float4 w = Wl[k * HID + lane];
            float sck = sc[k], shk = sh[k];
            float h0k = h0[k] * sck + shk;
            float h1k = h0[HID + k] * sck + shk;
            float h2k = h0[2 * HID + k] * sck + shk;
            float h3k = h0[3 * HID + k] * sck + shk;
            a0.x += h0k * w.x; a0.y += h0k * w.y; a0.z += h0k * w.z; a0.w += h0k * w.w;
            a1.x += h1k * w.x; a1.y += h1k * w.y; a1.z += h1k * w.z; a1.w += h1k * w.w;
            a2.x += h2k * w.x; a2.y += h2k * w.y; a2.z += h2k * w.z; a2.w += h2k * w.w;
            a3.x += h3k * w.x; a3.y += h3k * w.y; a3.z += h3k * w.z; a3.w += h3k * w.w;
        }
        size_t base = (size_t)r0 * HID + lane;
        pA[base + 0 * HID] = f2bf(a0.x) | (f2bf(a0.y) << 16);
        pA[base + 1 * HID] = f2bf(a1.x) | (f2bf(a1.y) << 16);
        pA[base + 2 * HID] = f2bf(a2.x) | (f2bf(a2.y) << 16);
        pA[base + 3 * HID] = f2bf(a3.x) | (f2bf(a3.y) << 16);
        pB[base + 0 * HID] = f2bf(a0.z) | (f2bf(a0.w) << 16);
        pB[base + 1 * HID] = f2bf(a1.z) | (f2bf(a1.w) << 16);
        pB[base + 2 * HID] = f2bf(a2.z) | (f2bf(a2.w) << 16);
        pB[base + 3 * HID] = f2bf(a3.z) | (f2bf(a3.w) << 16);
    }
}

// ---------------- nodeagg: MFMA edge-dots + gather epilogue, per-node waves --
// Wave owns contiguous node range; per <=16-edge chunk of a node:
//   phase A: A-frag loads (edges x 48k f16) -> 16 MFMA vs preloaded B-frags
//            -> dots[16 edges][128 j] in wave-private LDS
//   phase B: lane j walks edges: dsig/dsp from LDS + pA[src] gather + pB/bias
//            -> sigmoid*softplus -> acc. Plain store per node; BN stats fused.
__global__ __launch_bounds__(256) void k_nodeagg(const float* __restrict__ A,
                                                 const float* __restrict__ statsPrev,
                                                 const float* __restrict__ gammaP,
                                                 const float* __restrict__ betaP,
                                                 int applyBN,
                                                 const u32* __restrict__ pA,
                                                 const u32* __restrict__ pB,
                                                 const u32* __restrict__ eapS,
                                                 const int* __restrict__ srcS,
                                                 const int* __restrict__ rowptr,
                                                 const f16* __restrict__ Wf16L,
                                                 float* __restrict__ Aout,
                                                 float* __restrict__ statsOut) {
    __shared__ float dotsAll[4][16 * 132];   // per-wave [16 edges][132-padded 128 j]
    __shared__ float redS[256], redQ[256];
    const int lane = threadIdx.x & 63;
    float* dots = dotsAll[threadIdx.x >> 6];

    // preload B-fragments: 16 x f16x8 = 64 VGPRs
    const f16x8* WfL = (const f16x8*)Wf16L;
    f16x8 bfrag[2][8];
    #pragma unroll
    for (int kt = 0; kt < 2; ++kt)
        #pragma unroll
        for (int jt = 0; jt < 8; ++jt)
            bfrag[kt][jt] = WfL[(kt * 8 + jt) * 64 + lane];

    float scL = 1.f, shL = 0.f;
    if (applyBN) {
        float m = statsPrev[lane * 32] * (1.f / N_NODES);
        float v = statsPrev[(64 + lane) * 32] * (1.f / N_NODES) - m * m;
        scL = rsqrtf(v + BN_EPS) * gammaP[lane];
        shL = betaP[lane] - m * scL;
    }

    float lsum = 0.f, lsq = 0.f;
    const int wgid = __builtin_amdgcn_readfirstlane((blockIdx.x << 2) + (threadIdx.x >> 6));
    const int nwaves = gridDim.x << 2;
    const int cpw = (N_NODES + nwaves - 1) / nwaves;
    const int nb = wgid * cpw;
    const int ne = min(nb + cpw, N_NODES);

    for (int n = nb; n < ne; ++n) {
        const int rb = rowptr[n], re = rowptr[n + 1];
        float resid = A[(size_t)n * HID + lane];
        if (applyBN) resid = resid * scL + shL;
        const u32 pb = pB[(size_t)n * HID + lane];
        const float bsig = __uint_as_float(pb << 16);
        const float bsp = __uint_as_float(pb & 0xffff0000u);
        float acc = 0.f;
        for (int eb = rb; eb < re; eb += 16) {
            const int cnt = min(re - eb, 16);
            // ---- phase A: MFMA dots for this chunk ----
            const f16x8* arow = (const f16x8*)(eapS + (size_t)(eb + (lane & 15)) * 32);
            f16x8 a0 = arow[lane >> 4];        // k 0..31
            f16x8 a1 = arow[4 + (lane >> 4)];  // k 32..63 (zero-padded data)
            const int col = (lane & 15);
            const int rowb = (lane >> 4) * 4;
            #pragma unroll
            for (int jt = 0; jt < 8; ++jt) {
                f32x4 c = {};
                c = __builtin_amdgcn_mfma_f32_16x16x32_f16(a0, bfrag[0][jt], c, 0, 0, 0);
                c = __builtin_amdgcn_mfma_f32_16x16x32_f16(a1, bfrag[1][jt], c, 0, 0, 0);
                #pragma unroll
                for (int r = 0; r < 4; ++r)
                    dots[(rowb + r) * 132 + jt * 16 + col] = c[r];
            }
            // ---- phase B: gathers + epilogue, lane = output feature j ----
            u32 g[16];
            #pragma unroll
            for (int e = 0; e < 16; ++e)
                g[e] = (e < cnt) ? pA[(size_t)srcS[eb + e] * HID + lane] : 0u;
            #pragma unroll
            for (int e = 0; e < 16; ++e) {
                if (e < cnt) {
                    float dsig = dots[e * 132 + lane];
                    float dsp = dots[e * 132 + 64 + lane];
                    float s_ = dsig + __uint_as_float(g[e] << 16) + bsig;
                    float p_ = dsp + __uint_as_float(g[e] & 0xffff0000u) + bsp;
                    acc += edge_msg(s_, p_);
                }
            }
        }
        float outv = resid + acc;
        Aout[(size_t)n * HID + lane] = outv;
        lsum += outv;
        lsq += outv * outv;
    }

    redS[threadIdx.x] = lsum;
    redQ[threadIdx.x] = lsq;
    __syncthreads();
    if (threadIdx.x < 64) {
        float s = redS[threadIdx.x] + redS[threadIdx.x + 64] + redS[threadIdx.x + 128] + redS[threadIdx.x + 192];
        float q = redQ[threadIdx.x] + redQ[threadIdx.x + 64] + redQ[threadIdx.x + 128] + redQ[threadIdx.x + 192];
        unsafeAtomicAdd(&statsOut[threadIdx.x * 32], s);
        unsafeAtomicAdd(&statsOut[(64 + threadIdx.x) * 32], q);
    }
}

__global__ void k_zerof(float* __restrict__ p, int n) {
    int i = blockIdx.x * blockDim.x + threadIdx.x;
    if (i < n) p[i] = 0.f;
}

// ---------------- pool (+ final BN): segment-sum over sorted graph_idx ------
__global__ __launch_bounds__(256) void k_poolbn(const float* __restrict__ A,
                                                const float* __restrict__ stats,
                                                const float* __restrict__ gamma,
                                                const float* __restrict__ beta,
                                                const int* __restrict__ gidx,
                                                float* __restrict__ gf) {
    const int lane = threadIdx.x & 63;
    float m = stats[lane * 32] * (1.f / N_NODES);
    float v = stats[(64 + lane) * 32] * (1.f / N_NODES) - m * m;
    float scv = rsqrtf(v + BN_EPS) * gamma[lane];
    float shv = beta[lane] - m * scv;
    const int wid = blockIdx.x * 4 + (threadIdx.x >> 6);
    const int nwaves = gridDim.x * 4;
    const int chunk = (N_NODES + nwaves - 1) / nwaves;
    int r0 = wid * chunk;
    if (r0 >= N_NODES) return;
    int r1 = min(r0 + chunk, N_NODES);
    int gcur = gidx[r0];
    float acc = 0.f;
    for (int r = r0; r < r1; ++r) {
        int g = gidx[r];
        if (g != gcur) {
            unsafeAtomicAdd(&gf[(size_t)gcur * HID + lane], acc);
            acc = 0.f;
            gcur = g;
        }
        acc += A[(size_t)r * HID + lane] * scv + shv;
    }
    unsafeAtomicAdd(&gf[(size_t)gcur * HID + lane], acc);
}

// ---------------- readout ----------------
__global__ __launch_bounds__(256) void k_readout(const float* __restrict__ gf,
                                                 const float* __restrict__ Wfc,
                                                 const float* __restrict__ bfc,
                                                 const float* __restrict__ Wout,
                                                 const float* __restrict__ bout,
                                                 float* __restrict__ out) {
    const int lane = threadIdx.x & 63;
    const int g = blockIdx.x * 4 + (threadIdx.x >> 6);
    if (g >= N_GRAPHS) return;
    const float* row = gf + (size_t)g * HID;
    float p0 = bfc[lane], p1 = bfc[64 + lane];
    #pragma unroll 4
    for (int k = 0; k < HID; ++k) {
        float v = row[k];
        p0 += v * Wfc[k * PRED + lane];
        p1 += v * Wfc[k * PRED + 64 + lane];
    }
    float part = p0 * Wout[lane] + p1 * Wout[64 + lane];
    #pragma unroll
    for (int off = 32; off > 0; off >>= 1) part += __shfl_xor(part, off);
    if (lane == 0) out[g] = part + bout[0];
}

extern "C" void kernel_launch(void* const* d_in, const int* in_sizes, int n_in,
                              void* d_out, int out_size, void* d_ws, size_t ws_size,
                              hipStream_t stream) {
    const float* x         = (const float*)d_in[0];
    const float* edge_attr = (const float*)d_in[1];
    const int*   src       = (const int*)d_in[2];
    const int*   dst       = (const int*)d_in[3];
    const int*   gidx      = (const int*)d_in[4];
    const float* W_embed   = (const float*)d_in[6];
    const float* b_embed   = (const float*)d_in[7];
    const float* W_sig     = (const float*)d_in[8];
    const float* b_sig     = (const float*)d_in[9];
    const float* W_sp      = (const float*)d_in[10];
    const float* b_sp      = (const float*)d_in[11];
    const float* bn_gamma  = (const float*)d_in[12];
    const float* bn_beta   = (const float*)d_in[13];
    const float* W_fc      = (const float*)d_in[14];
    const float* b_fc      = (const float*)d_in[15];
    const float* W_out     = (const float*)d_in[16];
    const float* b_out     = (const float*)d_in[17];
    float* out = (float*)d_out;

    const size_t NH = (size_t)N_NODES * HID;
    float* ws     = (float*)d_ws;
    float* A      = ws;                                   // NH f32
    u32*   pA     = (u32*)(A + NH);                       // NH u32 (bf16x2)
    u32*   pB     = pA + NH;                              // NH u32
    u32*   eapS   = pB + NH;                              // (E+16)*32 u32 (f16, dst-sorted, 128B rows)
    int*   srcS   = (int*)(eapS + (size_t)(N_EDGES + 16) * 32);  // E
    int*   rowptr = srcS + N_EDGES;                       // N+1
    int*   deg    = rowptr + N_NODES + 1;                 // N
    int*   cursor = deg + N_NODES;                        // N
    int*   partial    = cursor + N_NODES;                 // 256
    int*   partialExc = partial + 256;                    // 256
    f16*   Wf16   = (f16*)(partialExc + 256);             // 3*2*8*64*8 f16 = 48 KB
    float* stats  = (float*)(Wf16 + 3 * 2 * 8 * 64 * 8);  // 3 * 4096 f32
    float* gf     = stats + 3 * 4096;                     // G*HID

    k_embed<<<512, 256, 0, stream>>>(x, W_embed, b_embed, A);

    // ---- CSR build + edge pack (once per call) ----
    k_zeroi<<<(2 * N_NODES + 255) / 256, 256, 0, stream>>>(deg, 2 * N_NODES);  // deg+cursor
    k_hist<<<(N_EDGES + 255) / 256, 256, 0, stream>>>(dst, deg);
    k_scanA<<<SCAN_BLOCKS, 256, 0, stream>>>(deg, partial);
    k_scanB<<<1, 256, 0, stream>>>(partial, partialExc, rowptr);
    k_scanC<<<SCAN_BLOCKS, 256, 0, stream>>>(deg, partialExc, rowptr);
    k_wprep<<<12, 256, 0, stream>>>(W_sig, W_sp, Wf16);
    k_rank<<<(N_EDGES + 255) / 256, 256, 0, stream>>>(dst, src, edge_attr, rowptr, cursor, srcS, eapS);

    for (int i = 0; i < 3; ++i) {
        const float* Wsig_i = W_sig + (size_t)i * ZDIM * HID;
        const float* Wsp_i  = W_sp + (size_t)i * ZDIM * HID;
        const float* stPrev = stats + (size_t)(i > 0 ? i - 1 : 0) * 4096;
        const float* gP     = bn_gamma + (i > 0 ? i - 1 : 0) * HID;
        const float* bP     = bn_beta + (i > 0 ? i - 1 : 0) * HID;
        float* stOut        = stats + (size_t)i * 4096;
        int applyBN = (i > 0) ? 1 : 0;
        k_proj<<<512, 256, 0, stream>>>(A, stPrev, gP, bP, applyBN,
                                        Wsig_i, b_sig + i * HID, Wsp_i, b_sp + i * HID,
                                        pA, pB, stOut);
        k_nodeagg<<<512, 256, 0, stream>>>(A, stPrev, gP, bP, applyBN,
                                           pA, pB, eapS, srcS, rowptr,
                                           Wf16 + (size_t)i * 2 * 8 * 64 * 8,
                                           A, stOut);
    }

    k_zerof<<<(N_GRAPHS * HID + 255) / 256, 256, 0, stream>>>(gf, N_GRAPHS * HID);
    k_poolbn<<<256, 256, 0, stream>>>(A, stats + 2 * 4096, bn_gamma + 2 * HID,
                                      bn_beta + 2 * HID, gidx, gf);
    k_readout<<<(N_GRAPHS + 3) / 4, 256, 0, stream>>>(gf, W_fc, b_fc, W_out, b_out, out);
}